// Round 8
// baseline (329.481 us; speedup 1.0000x reference)
//
#include <hip/hip_runtime.h>
#include <hip/hip_cooperative_groups.h>
#include <hip/hip_bf16.h>
#include <math.h>

namespace cg = cooperative_groups;

#define LTOT 36864      // 192*192
#define NH 4
#define NCHUNK 256
#define CHU 144
#define NBUCK 128
#define NSEG 144        // 36864 / 256
#define HW_ 192
#define VTS 148         // per-region VT row stride (u16)

typedef unsigned int u32;
typedef unsigned short u16;
typedef unsigned long long u64;
typedef __attribute__((ext_vector_type(4))) short short4v;
typedef __attribute__((ext_vector_type(4))) float f32x4;

__device__ __forceinline__ u32 pkbf(float a, float b){
  union { __hip_bfloat162 h2; u32 u; } cv;
  cv.h2 = __float22bfloat162_rn(float2{a,b});
  return cv.u;
}
__device__ __forceinline__ float bflo(u32 w){ return __uint_as_float(w<<16); }
__device__ __forceinline__ float bfhi(u32 w){ return __uint_as_float(w & 0xffff0000u); }

// ================= fused front-end (cooperative): conv -> hash+rank -> scan -> scatter =================
// Grid (NSEG,NH) x 256. Per-thread hash state (c, local rank, xe row) survives
// grid.sync() in registers -> no code/lrank arrays, no xe re-read in scatter.
__global__ __launch_bounds__(256, 3) void k_front(
    const float* __restrict__ x,  const float* __restrict__ wm,
    const float* __restrict__ bm, const float* __restrict__ wa,
    const float* __restrict__ ba, const float* __restrict__ rot,
    float* __restrict__ xe, float* __restrict__ ye,
    int* __restrict__ hist, int* __restrict__ segoff,
    int* __restrict__ rankof, u16* __restrict__ Ks, u16* __restrict__ Qs,
    u16* __restrict__ Vs)
{
  cg::grid_group grid = cg::this_grid();
  __shared__ float xs[3456];          // 32 ci x 6x18 halo (conv phase)
  __shared__ int wh[4][NBUCK];
  __shared__ int ps[2][NBUCK];
  __shared__ int tot[NBUCK], scv[NBUCK];

  const int t = threadIdx.x;
  const int seg = blockIdx.x, h = blockIdx.y;
  const int id = h*NSEG + seg;        // 0..575

  // ---------- phase 0: conv (16x4 px tile; wave w: 3x3 co {2w,2w+1} + 1x1 co 8w..8w+7) ----------
  {
    const int bx = id % 12, by = id / 12;
    for (int idx=t; idx<3456; idx+=256){
      int ci = idx/108, rem = idx-ci*108;
      int iy = rem/18,  ix = rem-iy*18;
      int yy = by*4+iy-1, xx = bx*16+ix-1;
      float v = 0.f;
      if (yy>=0 && yy<HW_ && xx>=0 && xx<HW_) v = x[ci*LTOT + yy*HW_ + xx];
      xs[idx] = v;
    }
    __syncthreads();
    const int lane = t & 63;
    const int w  = __builtin_amdgcn_readfirstlane(t>>6);
    const int co0 = 2*w, cb = 8*w;
    const int ix = lane & 15, iy = lane >> 4;
    float a0 = bm[co0], a1 = bm[co0+1];
    float acc[8];
    #pragma unroll
    for (int co=0;co<8;co++) acc[co] = ba[cb+co];
    const float* xb  = xs + iy*18 + ix;
    const float* w0p = wm + co0*288;
    const float* w1p = w0p + 288;
    for (int ci=0; ci<32; ci++){
      const float* xp = xb + ci*108;
      float x00=xp[0],  x01=xp[1],  x02=xp[2];
      float x10=xp[18], x11=xp[19], x12=xp[20];
      float x20=xp[36], x21=xp[37], x22=xp[38];
      const float* w0 = w0p + ci*9;
      const float* w1 = w1p + ci*9;
      a0 += x00*w0[0]+x01*w0[1]+x02*w0[2]
          + x10*w0[3]+x11*w0[4]+x12*w0[5]
          + x20*w0[6]+x21*w0[7]+x22*w0[8];
      a1 += x00*w1[0]+x01*w1[1]+x02*w1[2]
          + x10*w1[3]+x11*w1[4]+x12*w1[5]
          + x20*w1[6]+x21*w1[7]+x22*w1[8];
      const float* wap = wa + cb*32 + ci;
      #pragma unroll
      for (int co=0;co<8;co++) acc[co] += x11 * wap[co*32];
    }
    const int lc = (by*4+iy)*HW_ + bx*16+ix;
    *(float2*)(xe + lc*8 + co0) = float2{a0,a1};
    float4* yp = (float4*)(ye + lc*32 + cb);
    yp[0] = make_float4(acc[0],acc[1],acc[2],acc[3]);
    yp[1] = make_float4(acc[4],acc[5],acc[6],acc[7]);
  }
  grid.sync();

  // ---------- phase 1: hash + stable local rank (block = (seg,h)) ----------
  const int l = seg*256 + t;
  const float4* qp = (const float4*)(xe + l*8);
  float4 qa = qp[0], qb = qp[1];
  int c;
  {
    float best = -INFINITY; int bi = 0;
    float worst = INFINITY; int wi = 0;
    for (int i=0; i<64; i++){
      const float* rp = rot + h*64 + i;   // rot[f*256 + h*64 + i]
      float v = qa.x*rp[0]    + qa.y*rp[256]  + qa.z*rp[512]  + qa.w*rp[768]
              + qb.x*rp[1024] + qb.y*rp[1280] + qb.z*rp[1536] + qb.w*rp[1792];
      if (v > best)  { best  = v; bi = i; }
      if (v < worst) { worst = v; wi = i; }
    }
    c = (-worst > best) ? (64+wi) : bi;
  }
  int r_local;
  {
    const int lane = t & 63, w = t >> 6;
    u64 mask = ~0ull;
    #pragma unroll
    for (int bit=0; bit<7; bit++){
      u64 bset = __ballot((c>>bit)&1);
      mask &= ((c>>bit)&1) ? bset : ~bset;
    }
    int rin = __popcll(mask & ((lane==0)?0ull:(~0ull >> (64-lane))));
    int cnt = __popcll(mask);
    ((int*)wh)[t] = 0; ((int*)wh)[t+256] = 0;
    __syncthreads();
    if (rin == 0) wh[w][c] = cnt;
    __syncthreads();
    r_local = rin;
    for (int ww=0; ww<w; ww++) r_local += wh[ww][c];
    if (t < NBUCK) hist[(h*NSEG+seg)*NBUCK + t] = wh[0][t]+wh[1][t]+wh[2][t]+wh[3][t];
  }
  grid.sync();

  // ---------- phase 2: bucket/segment scan (4 blocks: seg==0) ----------
  if (seg == 0){
    const int b = t & 127, g = t >> 7;   // g: 0/1 -> segs g*72..g*72+71
    int sum = 0;
    for (int i=0;i<72;i++) sum += hist[(h*NSEG + g*72 + i)*NBUCK + b];
    ps[g][b] = sum;
    __syncthreads();
    if (g == 0){
      int run = 0;
      #pragma unroll
      for (int gg=0; gg<2; gg++){ int tv = ps[gg][b]; ps[gg][b] = run; run += tv; }
      tot[b] = run;
      int v = run;
      #pragma unroll
      for (int off=1; off<64; off<<=1){
        int u = __shfl_up(v, off);
        if ((b & 63) >= off) v += u;
      }
      scv[b] = v;
    }
    __syncthreads();
    int base = scv[b] - tot[b] + ((b >= 64) ? scv[63] : 0);
    int run2 = base + ps[g][b];
    for (int i=0;i<72;i++){
      segoff[(h*NSEG + g*72 + i)*NBUCK + b] = run2;
      run2 += hist[(h*NSEG + g*72 + i)*NBUCK + b];
    }
  }
  grid.sync();

  // ---------- phase 3: scatter (registers carried: qa,qb,c,r_local) ----------
  {
    int r = segoff[(h*NSEG+seg)*NBUCK + c] + r_local;
    rankof[h*LTOT + l] = r;
    float n2 = qa.x*qa.x+qa.y*qa.y+qa.z*qa.z+qa.w*qa.w
             + qb.x*qb.x+qb.y*qb.y+qb.z*qb.z+qb.w*qb.w;
    float sc = 1.0f / fmaxf(sqrtf(n2), 5e-5f);
    uint4 kk, qq;
    kk.x = pkbf(qa.x*sc,qa.y*sc); kk.y = pkbf(qa.z*sc,qa.w*sc);
    kk.z = pkbf(qb.x*sc,qb.y*sc); kk.w = pkbf(qb.z*sc,qb.w*sc);
    qq.x = pkbf(qa.x,qa.y); qq.y = pkbf(qa.z,qa.w);
    qq.z = pkbf(qb.x,qb.y); qq.w = pkbf(qb.z,qb.w);
    *(uint4*)(Ks + (size_t)(h*LTOT + r)*8) = kk;
    *(uint4*)(Qs + (size_t)(h*LTOT + r)*8) = qq;

    const float4* yr = (const float4*)(ye + l*32);
    uint4* vp = (uint4*)(Vs + (size_t)(h*LTOT + r)*32);
    #pragma unroll
    for (int e4=0; e4<4; e4++){
      float4 v0 = yr[2*e4], v1 = yr[2*e4+1];
      uint4 w;
      w.x = pkbf(v0.x,v0.y); w.y = pkbf(v0.z,v0.w);
      w.z = pkbf(v1.x,v1.y); w.w = pkbf(v1.z,v1.w);
      vp[e4] = w;
    }
  }
}

// ---------------- chunked attention: 5 waves x 2 query-tiles, register-prefetched region pipeline ----------------
__global__ __launch_bounds__(320) void k_attn(const u16* __restrict__ Ks,
    const u16* __restrict__ Qs, const u16* __restrict__ Vs,
    u16* __restrict__ ret_s, float* __restrict__ bs_s)
{
  __shared__ __align__(16) u16 Klds[CHU*8];
  __shared__ __align__(16) u16 Qlds[CHU*8];
  __shared__ __align__(16) u16 VT[32*VTS];
  __shared__ float qn[CHU];

  const int t = threadIdx.x;
  const int k = blockIdx.x, h = blockIdx.y;

  uint4 kpref;
  uint4 vpa0, vpa1, vpb0, vpb1;
  const int vp_i = t - 176, vp_p = vp_i >> 1, vp_hf = vp_i & 1;

  {
    const int gkb = ((k + NCHUNK-1) & (NCHUNK-1)) * CHU;
    if (t < CHU){
      kpref = *(const uint4*)(Ks + (size_t)(h*LTOT + gkb + t)*8);
      uint4 qv = *(const uint4*)(Qs + (size_t)(h*LTOT + k*CHU + t)*8);
      *(uint4*)(Qlds + t*8) = qv;
      float f0=bflo(qv.x), f1=bfhi(qv.x), f2=bflo(qv.y), f3=bfhi(qv.y);
      float f4=bflo(qv.z), f5=bfhi(qv.z), f6=bflo(qv.w), f7=bfhi(qv.w);
      qn[t] = sqrtf(f0*f0+f1*f1+f2*f2+f3*f3+f4*f4+f5*f5+f6*f6+f7*f7)*1.01f + 1e-6f;
    } else if (t >= 176){
      const uint4* ra = (const uint4*)(Vs + (size_t)(h*LTOT + gkb + 2*vp_p)*32);
      const uint4* rb = (const uint4*)(Vs + (size_t)(h*LTOT + gkb + 2*vp_p+1)*32);
      vpa0 = ra[vp_hf*2]; vpa1 = ra[vp_hf*2+1];
      vpb0 = rb[vp_hf*2]; vpb1 = rb[vp_hf*2+1];
    }
  }
  if (t < CHU){
    *(uint4*)(Klds + t*8) = kpref;
  } else if (t >= 176){
    u32 aw[8] = {vpa0.x,vpa0.y,vpa0.z,vpa0.w,vpa1.x,vpa1.y,vpa1.z,vpa1.w};
    u32 bw[8] = {vpb0.x,vpb0.y,vpb0.z,vpb0.w,vpb1.x,vpb1.y,vpb1.z,vpb1.w};
    int ebase = vp_hf*16;
    #pragma unroll
    for (int m=0;m<8;m++){
      u32 al = aw[m]&0xffffu, ah = aw[m]>>16;
      u32 bl = bw[m]&0xffffu, bh = bw[m]>>16;
      *(u32*)&VT[(ebase+2*m  )*VTS + 2*vp_p] = al | (bl<<16);
      *(u32*)&VT[(ebase+2*m+1)*VTS + 2*vp_p] = ah | (bh<<16);
    }
  }
  __syncthreads();

  const int lane = t & 63;
  const int wv = t >> 6;
  const int q = lane & 15;
  const int quad = lane >> 4;
  const int tl0 = 2*wv, tl1 = (2*wv+1 < 9) ? 2*wv+1 : 8;

  const short4v zs = {0,0,0,0};
  short4v bq0 = zs, bq1 = zs;
  if (quad < 2){
    bq0 = *(const short4v*)(Qlds + (tl0*16+q)*8 + quad*4);
    bq1 = *(const short4v*)(Qlds + (tl1*16+q)*8 + quad*4);
  }
  const float m0 = qn[tl0*16+q], m1 = qn[tl1*16+q];

  f32x4 o00={0,0,0,0}, o01={0,0,0,0}, o10={0,0,0,0}, o11={0,0,0,0};
  float s0 = 0.f, s1 = 0.f;

  for (int r=0; r<3; r++){
    if (r < 2){
      const int gkb = ((k + NCHUNK + r) & (NCHUNK-1)) * CHU;
      if (t < CHU){
        kpref = *(const uint4*)(Ks + (size_t)(h*LTOT + gkb + t)*8);
      } else if (t >= 176){
        const uint4* ra = (const uint4*)(Vs + (size_t)(h*LTOT + gkb + 2*vp_p)*32);
        const uint4* rb = (const uint4*)(Vs + (size_t)(h*LTOT + gkb + 2*vp_p+1)*32);
        vpa0 = ra[vp_hf*2]; vpa1 = ra[vp_hf*2+1];
        vpb0 = rb[vp_hf*2]; vpb1 = rb[vp_hf*2+1];
      }
    }

    #pragma unroll 3
    for (int kt=0; kt<9; kt++){
      short4v av = zs;
      if (quad < 2) av = *(const short4v*)(Klds + (kt*16+q)*8 + quad*4);
      f32x4 zc = {0.f,0.f,0.f,0.f};
      f32x4 stA = __builtin_amdgcn_mfma_f32_16x16x16bf16_1k(av, bq0, zc, 0,0,0);
      f32x4 stB = __builtin_amdgcn_mfma_f32_16x16x16bf16_1k(av, bq1, zc, 0,0,0);

      float pA0 = __expf(stA[0]-m0), pA1 = __expf(stA[1]-m0);
      float pA2 = __expf(stA[2]-m0), pA3 = __expf(stA[3]-m0);
      float pB0 = __expf(stB[0]-m1), pB1 = __expf(stB[1]-m1);
      float pB2 = __expf(stB[2]-m1), pB3 = __expf(stB[3]-m1);
      s0 += (pA0+pA1)+(pA2+pA3);
      s1 += (pB0+pB1)+(pB2+pB3);

      union { u32 u[2]; short4v s4; } pkA, pkB;
      pkA.u[0] = pkbf(pA0,pA1); pkA.u[1] = pkbf(pA2,pA3);
      pkB.u[0] = pkbf(pB0,pB1); pkB.u[1] = pkbf(pB2,pB3);

      short4v va0 = *(const short4v*)(&VT[ q    *VTS + kt*16 + quad*4]);
      short4v va1 = *(const short4v*)(&VT[(q+16)*VTS + kt*16 + quad*4]);
      o00 = __builtin_amdgcn_mfma_f32_16x16x16bf16_1k(va0, pkA.s4, o00, 0,0,0);
      o01 = __builtin_amdgcn_mfma_f32_16x16x16bf16_1k(va1, pkA.s4, o01, 0,0,0);
      o10 = __builtin_amdgcn_mfma_f32_16x16x16bf16_1k(va0, pkB.s4, o10, 0,0,0);
      o11 = __builtin_amdgcn_mfma_f32_16x16x16bf16_1k(va1, pkB.s4, o11, 0,0,0);
    }

    if (r < 2){
      __syncthreads();
      if (t < CHU){
        *(uint4*)(Klds + t*8) = kpref;
      } else if (t >= 176){
        u32 aw[8] = {vpa0.x,vpa0.y,vpa0.z,vpa0.w,vpa1.x,vpa1.y,vpa1.z,vpa1.w};
        u32 bw[8] = {vpb0.x,vpb0.y,vpb0.z,vpb0.w,vpb1.x,vpb1.y,vpb1.z,vpb1.w};
        int ebase = vp_hf*16;
        #pragma unroll
        for (int m=0;m<8;m++){
          u32 al = aw[m]&0xffffu, ah = aw[m]>>16;
          u32 bl = bw[m]&0xffffu, bh = bw[m]>>16;
          *(u32*)&VT[(ebase+2*m  )*VTS + 2*vp_p] = al | (bl<<16);
          *(u32*)&VT[(ebase+2*m+1)*VTS + 2*vp_p] = ah | (bh<<16);
        }
      }
      __syncthreads();
    }
  }

  float st0 = s0, st1 = s1;
  st0 += __shfl_xor(st0, 16); st0 += __shfl_xor(st0, 32);
  st1 += __shfl_xor(st1, 16); st1 += __shfl_xor(st1, 32);
  float inv0 = 1.0f/st0, inv1 = 1.0f/st1;

  const int row0 = h*LTOT + k*CHU + tl0*16 + q;
  const int row1 = h*LTOT + k*CHU + tl1*16 + q;
  u16* rp0 = ret_s + (size_t)row0*32;
  u16* rp1 = ret_s + (size_t)row1*32;
  uint2 wA, wB;
  wA.x = pkbf(o00[0]*inv0, o00[1]*inv0); wA.y = pkbf(o00[2]*inv0, o00[3]*inv0);
  wB.x = pkbf(o01[0]*inv0, o01[1]*inv0); wB.y = pkbf(o01[2]*inv0, o01[3]*inv0);
  *(uint2*)&rp0[quad*4]    = wA;
  *(uint2*)&rp0[16+quad*4] = wB;
  wA.x = pkbf(o10[0]*inv1, o10[1]*inv1); wA.y = pkbf(o10[2]*inv1, o10[3]*inv1);
  wB.x = pkbf(o11[0]*inv1, o11[1]*inv1); wB.y = pkbf(o11[2]*inv1, o11[3]*inv1);
  *(uint2*)&rp1[quad*4]    = wA;
  *(uint2*)&rp1[16+quad*4] = wB;
  if (quad == 0){
    bs_s[row0] = m0 + __logf(st0);
    bs_s[row1] = m1 + __logf(st1);
  }
}

// ---------------- unsort gather + cross-hash softmax + residual (warp-per-8-elems) ----------------
__global__ __launch_bounds__(256) void k_final(const float* __restrict__ x,
    const int* __restrict__ rankof, const u16* __restrict__ ret_s,
    const float* __restrict__ bs_s, float* __restrict__ out)
{
  const int l  = blockIdx.x*64 + (threadIdx.x & 63);
  const int eg = threadIdx.x >> 6;
  int r[NH]; float bs[NH];
  #pragma unroll
  for (int h=0;h<NH;h++) r[h] = rankof[h*LTOT + l];
  #pragma unroll
  for (int h=0;h<NH;h++) bs[h] = bs_s[h*LTOT + r[h]];
  float m = fmaxf(fmaxf(bs[0],bs[1]), fmaxf(bs[2],bs[3]));
  float p[NH]; float s = 0.f;
  #pragma unroll
  for (int h=0;h<NH;h++){ p[h] = __expf(bs[h]-m); s += p[h]; }
  float inv = 1.0f/s;
  float o[8];
  #pragma unroll
  for (int e=0;e<8;e++) o[e]=0.f;
  #pragma unroll
  for (int h=0;h<NH;h++){
    float w = p[h]*inv;
    uint4 v = *(const uint4*)(ret_s + (size_t)(h*LTOT + r[h])*32 + eg*8);
    o[0] += w*bflo(v.x); o[1] += w*bfhi(v.x);
    o[2] += w*bflo(v.y); o[3] += w*bfhi(v.y);
    o[4] += w*bflo(v.z); o[5] += w*bfhi(v.z);
    o[6] += w*bflo(v.w); o[7] += w*bfhi(v.w);
  }
  #pragma unroll
  for (int e=0;e<8;e++){
    int ge = eg*8 + e;
    out[ge*LTOT + l] = o[e] + x[ge*LTOT + l];
  }
}

extern "C" void kernel_launch(void* const* d_in, const int* in_sizes, int n_in,
                              void* d_out, int out_size, void* d_ws, size_t ws_size,
                              hipStream_t stream)
{
  const float* x   = (const float*)d_in[0];
  const float* wm  = (const float*)d_in[1];
  const float* bm  = (const float*)d_in[2];
  const float* wa  = (const float*)d_in[3];
  const float* ba  = (const float*)d_in[4];
  const float* rot = (const float*)d_in[5];
  float* out = (float*)d_out;

  char* ws = (char*)d_ws;
  size_t off = 0;
  auto alloc = [&](size_t bytes)->void*{
    void* p = ws + off;
    off = (off + bytes + 255) & ~(size_t)255;
    return p;
  };
  float* xe     = (float*)alloc((size_t)LTOT*8*4);
  float* ye     = (float*)alloc((size_t)LTOT*32*4);
  int*   hist   = (int*)  alloc((size_t)NH*NSEG*NBUCK*4);
  int*   segoff = (int*)  alloc((size_t)NH*NSEG*NBUCK*4);
  int*   rankof = (int*)  alloc((size_t)NH*LTOT*4);
  u16*   Ks     = (u16*)  alloc((size_t)NH*LTOT*8*2);
  u16*   Qs     = (u16*)  alloc((size_t)NH*LTOT*8*2);
  u16*   Vs     = (u16*)  alloc((size_t)NH*LTOT*32*2);
  u16*   ret_s  = (u16*)  alloc((size_t)NH*LTOT*32*2);
  float* bs_s   = (float*)alloc((size_t)NH*LTOT*4);

  void* fargs[] = { (void*)&x, (void*)&wm, (void*)&bm, (void*)&wa, (void*)&ba,
                    (void*)&rot, (void*)&xe, (void*)&ye, (void*)&hist,
                    (void*)&segoff, (void*)&rankof, (void*)&Ks, (void*)&Qs,
                    (void*)&Vs };
  hipLaunchCooperativeKernel((const void*)k_front, dim3(NSEG,NH), dim3(256),
                             fargs, 0, stream);
  hipLaunchKernelGGL(k_attn,  dim3(NCHUNK,NH), dim3(320), 0, stream, Ks, Qs, Vs, ret_s, bs_s);
  hipLaunchKernelGGL(k_final, dim3(576),       dim3(256), 0, stream, x, rankof, ret_s, bs_s, out);
}

// Round 9
// 130.519 us; speedup vs baseline: 2.5244x; 2.5244x over previous
//
#include <hip/hip_runtime.h>
#include <hip/hip_bf16.h>
#include <math.h>

#define LTOT 36864      // 192*192
#define NH 4
#define NCHUNK 256
#define CHU 144
#define NBUCK 128
#define NSEG 144        // 36864 / 256
#define HW_ 192
#define VTS 148         // per-region VT row stride (u16)

typedef unsigned int u32;
typedef unsigned short u16;
typedef unsigned long long u64;
typedef __attribute__((ext_vector_type(4))) short short4v;
typedef __attribute__((ext_vector_type(4))) float f32x4;

__device__ __forceinline__ u32 pkbf(float a, float b){
  union { __hip_bfloat162 h2; u32 u; } cv;
  cv.h2 = __float22bfloat162_rn(float2{a,b});
  return cv.u;
}
__device__ __forceinline__ float bflo(u32 w){ return __uint_as_float(w<<16); }
__device__ __forceinline__ float bfhi(u32 w){ return __uint_as_float(w & 0xffff0000u); }

// ---------------- conv: 576 blocks, 16x4 px tile; wave w: 3x3 co-pair {2w,2w+1} (fp32 xe)
//                  + 1x1 co 8w..8w+7 written DIRECTLY as bf16 Vu rows ----------------
__global__ __launch_bounds__(256) void k_conv(const float* __restrict__ x,
    const float* __restrict__ wm, const float* __restrict__ bm,
    const float* __restrict__ wa, const float* __restrict__ ba,
    float* __restrict__ xe, u16* __restrict__ Vu)
{
  __shared__ float xs[32*108];   // 32 ci x 6x18 halo
  const int t = threadIdx.x;
  const int id = blockIdx.x;
  const int bx = id % 12, by = id / 12;

  for (int idx=t; idx<3456; idx+=256){
    int ci = idx/108, rem = idx-ci*108;
    int iy = rem/18,  ix = rem-iy*18;
    int yy = by*4+iy-1, xx = bx*16+ix-1;
    float v = 0.f;
    if (yy>=0 && yy<HW_ && xx>=0 && xx<HW_) v = x[ci*LTOT + yy*HW_ + xx];
    xs[idx] = v;
  }
  __syncthreads();
  const int lane = t & 63;
  const int w  = __builtin_amdgcn_readfirstlane(t>>6);
  const int co0 = 2*w, cb = 8*w;
  const int ix = lane & 15, iy = lane >> 4;
  float a0 = bm[co0], a1 = bm[co0+1];
  float acc[8];
  #pragma unroll
  for (int co=0;co<8;co++) acc[co] = ba[cb+co];
  const float* xb  = xs + iy*18 + ix;
  const float* w0p = wm + co0*288;
  const float* w1p = w0p + 288;
  for (int ci=0; ci<32; ci++){
    const float* xp = xb + ci*108;
    float x00=xp[0],  x01=xp[1],  x02=xp[2];
    float x10=xp[18], x11=xp[19], x12=xp[20];
    float x20=xp[36], x21=xp[37], x22=xp[38];
    const float* w0 = w0p + ci*9;
    const float* w1 = w1p + ci*9;
    a0 += x00*w0[0]+x01*w0[1]+x02*w0[2]
        + x10*w0[3]+x11*w0[4]+x12*w0[5]
        + x20*w0[6]+x21*w0[7]+x22*w0[8];
    a1 += x00*w1[0]+x01*w1[1]+x02*w1[2]
        + x10*w1[3]+x11*w1[4]+x12*w1[5]
        + x20*w1[6]+x21*w1[7]+x22*w1[8];
    const float* wap = wa + cb*32 + ci;
    #pragma unroll
    for (int co=0;co<8;co++) acc[co] += x11 * wap[co*32];
  }
  const int l = (by*4+iy)*HW_ + bx*16+ix;
  *(float2*)(xe + l*8 + co0) = float2{a0,a1};
  uint4 vv;
  vv.x = pkbf(acc[0],acc[1]); vv.y = pkbf(acc[2],acc[3]);
  vv.z = pkbf(acc[4],acc[5]); vv.w = pkbf(acc[6],acc[7]);
  *(uint4*)(Vu + (size_t)l*32 + cb) = vv;
}

// ---------------- hash + stable local rank (merged), ballot-based ----------------
__global__ __launch_bounds__(256) void k_hashrank(const float* __restrict__ xe,
    const float* __restrict__ rot, int* __restrict__ code,
    int* __restrict__ lrank, int* __restrict__ hist)
{
  const int h = blockIdx.y, seg = blockIdx.x, t = threadIdx.x;
  const int l = seg*256 + t;
  const float4* qp = (const float4*)(xe + l*8);
  float4 qa = qp[0], qb = qp[1];
  float best = -INFINITY; int bi = 0;
  float worst = INFINITY; int wi = 0;
  for (int i=0; i<64; i++){
    const float* rp = rot + h*64 + i;   // rot[f*256 + h*64 + i]
    float v = qa.x*rp[0]    + qa.y*rp[256]  + qa.z*rp[512]  + qa.w*rp[768]
            + qb.x*rp[1024] + qb.y*rp[1280] + qb.z*rp[1536] + qb.w*rp[1792];
    if (v > best)  { best  = v; bi = i; }
    if (v < worst) { worst = v; wi = i; }
  }
  int c = (-worst > best) ? (64+wi) : bi;
  code[h*LTOT + l] = c;

  const int lane = t & 63, w = t >> 6;
  u64 mask = ~0ull;
  #pragma unroll
  for (int bit=0; bit<7; bit++){
    u64 bset = __ballot((c>>bit)&1);
    mask &= ((c>>bit)&1) ? bset : ~bset;
  }
  int rin = __popcll(mask & ((lane==0)?0ull:(~0ull >> (64-lane))));
  int cnt = __popcll(mask);

  __shared__ int wh[4][NBUCK];
  ((int*)wh)[t] = 0; ((int*)wh)[t+256] = 0;
  __syncthreads();
  if (rin == 0) wh[w][c] = cnt;
  __syncthreads();
  int r = rin;
  for (int ww=0; ww<w; ww++) r += wh[ww][c];
  lrank[h*LTOT + l] = r;
  if (t < NBUCK) hist[(h*NSEG+seg)*NBUCK + t] = wh[0][t]+wh[1][t]+wh[2][t]+wh[3][t];
}

// ---------------- bucket/segment prefix scan: 512 thr, 4 segment-groups, reg-cached ----------------
__global__ __launch_bounds__(512) void k_scan(const int* __restrict__ hist,
    int* __restrict__ segoff)
{
  const int h = blockIdx.x;
  const int b = threadIdx.x & 127, g = threadIdx.x >> 7;
  int vals[36];
  int sum = 0;
  #pragma unroll
  for (int i=0;i<36;i++){
    vals[i] = hist[(h*NSEG + g*36 + i)*NBUCK + b];
    sum += vals[i];
  }
  __shared__ int ps[4][NBUCK];
  __shared__ int tot[NBUCK];
  __shared__ int scv[NBUCK];
  ps[g][b] = sum;
  __syncthreads();
  if (g == 0){
    int run = 0;
    #pragma unroll
    for (int gg=0; gg<4; gg++){ int tv = ps[gg][b]; ps[gg][b] = run; run += tv; }
    tot[b] = run;
    int v = run;
    #pragma unroll
    for (int off=1; off<64; off<<=1){
      int u = __shfl_up(v, off);
      if ((b & 63) >= off) v += u;
    }
    scv[b] = v;
  }
  __syncthreads();
  int base = scv[b] - tot[b] + ((b >= 64) ? scv[63] : 0);
  int run2 = base + ps[g][b];
  #pragma unroll
  for (int i=0;i<36;i++){
    segoff[(h*NSEG + g*36 + i)*NBUCK + b] = run2;
    run2 += vals[i];
  }
}

// ---------------- scatter: sorted bf16 K/Q (16B rows), V (64B row copy), spos ----------------
__global__ __launch_bounds__(256) void k_scatter(const int* __restrict__ code,
    const int* __restrict__ lrank, const int* __restrict__ segoff,
    const float* __restrict__ xe, const u16* __restrict__ Vu,
    int* __restrict__ spos, u16* __restrict__ Ks, u16* __restrict__ Qs,
    u16* __restrict__ Vs)
{
  const int h = blockIdx.y, seg = blockIdx.x, t = threadIdx.x;
  const int l = seg*256 + t;
  int c = code[h*LTOT + l];
  int r = segoff[(h*NSEG+seg)*NBUCK + c] + lrank[h*LTOT + l];
  spos[h*LTOT + r] = l;

  const float4* xr = (const float4*)(xe + l*8);
  float4 a = xr[0], b = xr[1];
  float n2 = a.x*a.x+a.y*a.y+a.z*a.z+a.w*a.w
           + b.x*b.x+b.y*b.y+b.z*b.z+b.w*b.w;
  float sc = 1.0f / fmaxf(sqrtf(n2), 5e-5f);
  uint4 kk, qq;
  kk.x = pkbf(a.x*sc,a.y*sc); kk.y = pkbf(a.z*sc,a.w*sc);
  kk.z = pkbf(b.x*sc,b.y*sc); kk.w = pkbf(b.z*sc,b.w*sc);
  qq.x = pkbf(a.x,a.y); qq.y = pkbf(a.z,a.w);
  qq.z = pkbf(b.x,b.y); qq.w = pkbf(b.z,b.w);
  *(uint4*)(Ks + (size_t)(h*LTOT + r)*8) = kk;
  *(uint4*)(Qs + (size_t)(h*LTOT + r)*8) = qq;

  const uint4* vr = (const uint4*)(Vu + (size_t)l*32);
  uint4* vp = (uint4*)(Vs + (size_t)(h*LTOT + r)*32);
  vp[0] = vr[0]; vp[1] = vr[1]; vp[2] = vr[2]; vp[3] = vr[3];
}

// ---------------- chunked attention: 5 waves (4x2 + 1x1 query tiles), region-phased;
//                  outputs scattered directly to UNSORTED order (64B row stores) ----------------
__global__ __launch_bounds__(320) void k_attn(const u16* __restrict__ Ks,
    const u16* __restrict__ Qs, const u16* __restrict__ Vs,
    const int* __restrict__ spos, u16* __restrict__ ret_u, float* __restrict__ bs_u)
{
  __shared__ __align__(16) u16 Klds[CHU*8];
  __shared__ __align__(16) u16 Qlds[CHU*8];
  __shared__ __align__(16) u16 VT[32*VTS];
  __shared__ float qn[CHU];
  __shared__ int spos_l[CHU];

  const int t = threadIdx.x;
  const int k = blockIdx.x, h = blockIdx.y;

  // stage Q + qn + spos once
  if (t < CHU){
    uint4 qv = *(const uint4*)(Qs + (size_t)(h*LTOT + k*CHU + t)*8);
    *(uint4*)(Qlds + t*8) = qv;
    float f0=bflo(qv.x), f1=bfhi(qv.x), f2=bflo(qv.y), f3=bfhi(qv.y);
    float f4=bflo(qv.z), f5=bfhi(qv.z), f6=bflo(qv.w), f7=bfhi(qv.w);
    qn[t] = sqrtf(f0*f0+f1*f1+f2*f2+f3*f3+f4*f4+f5*f5+f6*f6+f7*f7)*1.01f + 1e-6f;
    spos_l[t] = spos[h*LTOT + k*CHU + t];
  }
  __syncthreads();

  const int lane = t & 63;
  const int wv = t >> 6;                 // 0..4
  const int q = lane & 15;
  const int quad = lane >> 4;
  const bool two = (wv < 4);
  const int tl0 = 2*wv;                  // 0,2,4,6,8
  const int tl1 = two ? (2*wv+1) : 8;    // second tile (wave4: unused, safe idx)

  const short4v zs = {0,0,0,0};
  short4v bq0 = zs, bq1 = zs;
  if (quad < 2){
    bq0 = *(const short4v*)(Qlds + (tl0*16+q)*8 + quad*4);
    if (two) bq1 = *(const short4v*)(Qlds + (tl1*16+q)*8 + quad*4);
  }
  const float m0 = qn[tl0*16+q];
  const float m1 = two ? qn[tl1*16+q] : 0.f;

  f32x4 o00={0,0,0,0}, o01={0,0,0,0}, o10={0,0,0,0}, o11={0,0,0,0};
  float s0 = 0.f, s1 = 0.f;

  for (int r=0; r<3; r++){
    __syncthreads();     // previous region compute done
    const int gkb = ((k + NCHUNK-1 + r) & (NCHUNK-1)) * CHU;
    if (t < CHU){
      *(uint4*)(Klds + t*8) = *(const uint4*)(Ks + (size_t)(h*LTOT + gkb + t)*8);
    } else if (t >= 176){
      int i = t - 176;
      int p = i >> 1, hf = i & 1;
      const uint4* ra = (const uint4*)(Vs + (size_t)(h*LTOT + gkb + 2*p)*32);
      const uint4* rb = (const uint4*)(Vs + (size_t)(h*LTOT + gkb + 2*p+1)*32);
      uint4 A0 = ra[hf*2], A1 = ra[hf*2+1];
      uint4 B0 = rb[hf*2], B1 = rb[hf*2+1];
      u32 aw[8] = {A0.x,A0.y,A0.z,A0.w,A1.x,A1.y,A1.z,A1.w};
      u32 bw[8] = {B0.x,B0.y,B0.z,B0.w,B1.x,B1.y,B1.z,B1.w};
      int ebase = hf*16;
      #pragma unroll
      for (int m=0;m<8;m++){
        u32 al = aw[m]&0xffffu, ah = aw[m]>>16;
        u32 bl = bw[m]&0xffffu, bh = bw[m]>>16;
        *(u32*)&VT[(ebase+2*m  )*VTS + 2*p] = al | (bl<<16);
        *(u32*)&VT[(ebase+2*m+1)*VTS + 2*p] = ah | (bh<<16);
      }
    }
    __syncthreads();

    #pragma unroll 3
    for (int kt=0; kt<9; kt++){
      short4v av = zs;
      if (quad < 2) av = *(const short4v*)(Klds + (kt*16+q)*8 + quad*4);
      f32x4 zc = {0.f,0.f,0.f,0.f};
      f32x4 stA = __builtin_amdgcn_mfma_f32_16x16x16bf16_1k(av, bq0, zc, 0,0,0);

      float pA0 = __expf(stA[0]-m0), pA1 = __expf(stA[1]-m0);
      float pA2 = __expf(stA[2]-m0), pA3 = __expf(stA[3]-m0);
      s0 += (pA0+pA1)+(pA2+pA3);
      union { u32 u[2]; short4v s4; } pkA;
      pkA.u[0] = pkbf(pA0,pA1); pkA.u[1] = pkbf(pA2,pA3);

      short4v va0 = *(const short4v*)(&VT[ q    *VTS + kt*16 + quad*4]);
      short4v va1 = *(const short4v*)(&VT[(q+16)*VTS + kt*16 + quad*4]);
      o00 = __builtin_amdgcn_mfma_f32_16x16x16bf16_1k(va0, pkA.s4, o00, 0,0,0);
      o01 = __builtin_amdgcn_mfma_f32_16x16x16bf16_1k(va1, pkA.s4, o01, 0,0,0);

      if (two){
        f32x4 stB = __builtin_amdgcn_mfma_f32_16x16x16bf16_1k(av, bq1, zc, 0,0,0);
        float pB0 = __expf(stB[0]-m1), pB1 = __expf(stB[1]-m1);
        float pB2 = __expf(stB[2]-m1), pB3 = __expf(stB[3]-m1);
        s1 += (pB0+pB1)+(pB2+pB3);
        union { u32 u[2]; short4v s4; } pkB;
        pkB.u[0] = pkbf(pB0,pB1); pkB.u[1] = pkbf(pB2,pB3);
        o10 = __builtin_amdgcn_mfma_f32_16x16x16bf16_1k(va0, pkB.s4, o10, 0,0,0);
        o11 = __builtin_amdgcn_mfma_f32_16x16x16bf16_1k(va1, pkB.s4, o11, 0,0,0);
      }
    }
  }

  float st0 = s0;
  st0 += __shfl_xor(st0, 16); st0 += __shfl_xor(st0, 32);
  float inv0 = 1.0f/st0;

  // scatter 64B row to UNSORTED position
  const int pos0 = spos_l[tl0*16 + q];
  u16* rp0 = ret_u + (size_t)(h*LTOT + pos0)*32;
  uint2 wA, wB;
  wA.x = pkbf(o00[0]*inv0, o00[1]*inv0); wA.y = pkbf(o00[2]*inv0, o00[3]*inv0);
  wB.x = pkbf(o01[0]*inv0, o01[1]*inv0); wB.y = pkbf(o01[2]*inv0, o01[3]*inv0);
  *(uint2*)&rp0[quad*4]    = wA;
  *(uint2*)&rp0[16+quad*4] = wB;
  if (quad == 0) bs_u[h*LTOT + pos0] = m0 + __logf(st0);

  if (two){
    float st1 = s1;
    st1 += __shfl_xor(st1, 16); st1 += __shfl_xor(st1, 32);
    float inv1 = 1.0f/st1;
    const int pos1 = spos_l[tl1*16 + q];
    u16* rp1 = ret_u + (size_t)(h*LTOT + pos1)*32;
    wA.x = pkbf(o10[0]*inv1, o10[1]*inv1); wA.y = pkbf(o10[2]*inv1, o10[3]*inv1);
    wB.x = pkbf(o11[0]*inv1, o11[1]*inv1); wB.y = pkbf(o11[2]*inv1, o11[3]*inv1);
    *(uint2*)&rp1[quad*4]    = wA;
    *(uint2*)&rp1[16+quad*4] = wB;
    if (quad == 0) bs_u[h*LTOT + pos1] = m1 + __logf(st1);
  }
}

// ---------------- cross-hash softmax + residual — fully coalesced ----------------
__global__ __launch_bounds__(256) void k_final(const float* __restrict__ x,
    const u16* __restrict__ ret_u, const float* __restrict__ bs_u,
    float* __restrict__ out)
{
  const int l  = blockIdx.x*64 + (threadIdx.x & 63);
  const int eg = threadIdx.x >> 6;        // 0..3 -> elems eg*8..eg*8+7
  float bs[NH];
  #pragma unroll
  for (int h=0;h<NH;h++) bs[h] = bs_u[h*LTOT + l];
  float m = fmaxf(fmaxf(bs[0],bs[1]), fmaxf(bs[2],bs[3]));
  float p[NH]; float s = 0.f;
  #pragma unroll
  for (int h=0;h<NH;h++){ p[h] = __expf(bs[h]-m); s += p[h]; }
  float inv = 1.0f/s;
  float o[8];
  #pragma unroll
  for (int e=0;e<8;e++) o[e]=0.f;
  #pragma unroll
  for (int h=0;h<NH;h++){
    float w = p[h]*inv;
    uint4 v = *(const uint4*)(ret_u + (size_t)(h*LTOT + l)*32 + eg*8);
    o[0] += w*bflo(v.x); o[1] += w*bfhi(v.x);
    o[2] += w*bflo(v.y); o[3] += w*bfhi(v.y);
    o[4] += w*bflo(v.z); o[5] += w*bfhi(v.z);
    o[6] += w*bflo(v.w); o[7] += w*bfhi(v.w);
  }
  #pragma unroll
  for (int e=0;e<8;e++){
    int ge = eg*8 + e;
    out[ge*LTOT + l] = o[e] + x[ge*LTOT + l];
  }
}

extern "C" void kernel_launch(void* const* d_in, const int* in_sizes, int n_in,
                              void* d_out, int out_size, void* d_ws, size_t ws_size,
                              hipStream_t stream)
{
  const float* x   = (const float*)d_in[0];
  const float* wm  = (const float*)d_in[1];
  const float* bm  = (const float*)d_in[2];
  const float* wa  = (const float*)d_in[3];
  const float* ba  = (const float*)d_in[4];
  const float* rot = (const float*)d_in[5];
  float* out = (float*)d_out;

  char* ws = (char*)d_ws;
  size_t off = 0;
  auto alloc = [&](size_t bytes)->void*{
    void* p = ws + off;
    off = (off + bytes + 255) & ~(size_t)255;
    return p;
  };
  float* xe     = (float*)alloc((size_t)LTOT*8*4);
  u16*   Vu     = (u16*)  alloc((size_t)LTOT*32*2);
  int*   code   = (int*)  alloc((size_t)NH*LTOT*4);
  int*   lrank  = (int*)  alloc((size_t)NH*LTOT*4);
  int*   hist   = (int*)  alloc((size_t)NH*NSEG*NBUCK*4);
  int*   segoff = (int*)  alloc((size_t)NH*NSEG*NBUCK*4);
  int*   spos   = (int*)  alloc((size_t)NH*LTOT*4);
  u16*   Ks     = (u16*)  alloc((size_t)NH*LTOT*8*2);
  u16*   Qs     = (u16*)  alloc((size_t)NH*LTOT*8*2);
  u16*   Vs     = (u16*)  alloc((size_t)NH*LTOT*32*2);
  u16*   ret_u  = (u16*)  alloc((size_t)NH*LTOT*32*2);
  float* bs_u   = (float*)alloc((size_t)NH*LTOT*4);

  hipLaunchKernelGGL(k_conv,     dim3(576),        dim3(256), 0, stream, x, wm, bm, wa, ba, xe, Vu);
  hipLaunchKernelGGL(k_hashrank, dim3(NSEG,NH),    dim3(256), 0, stream, xe, rot, code, lrank, hist);
  hipLaunchKernelGGL(k_scan,     dim3(NH),         dim3(512), 0, stream, hist, segoff);
  hipLaunchKernelGGL(k_scatter,  dim3(NSEG,NH),    dim3(256), 0, stream, code, lrank, segoff, xe, Vu, spos, Ks, Qs, Vs);
  hipLaunchKernelGGL(k_attn,     dim3(NCHUNK,NH),  dim3(320), 0, stream, Ks, Qs, Vs, spos, ret_u, bs_u);
  hipLaunchKernelGGL(k_final,    dim3(576),        dim3(256), 0, stream, x, ret_u, bs_u, out);
}

// Round 10
// 130.024 us; speedup vs baseline: 2.5340x; 1.0038x over previous
//
#include <hip/hip_runtime.h>
#include <hip/hip_bf16.h>
#include <math.h>

#define LTOT 36864      // 192*192
#define NH 4
#define NCHUNK 256
#define CHU 144
#define NBUCK 128
#define NSEG 144        // 36864 / 256
#define HW_ 192
#define VTS 148         // VT row stride (u16)

typedef unsigned int u32;
typedef unsigned short u16;
typedef unsigned long long u64;
typedef __attribute__((ext_vector_type(4))) short short4v;
typedef __attribute__((ext_vector_type(4))) float f32x4;

__device__ __forceinline__ u32 pkbf(float a, float b){
  union { __hip_bfloat162 h2; u32 u; } cv;
  cv.h2 = __float22bfloat162_rn(float2{a,b});
  return cv.u;
}
__device__ __forceinline__ float bflo(u32 w){ return __uint_as_float(w<<16); }
__device__ __forceinline__ float bfhi(u32 w){ return __uint_as_float(w & 0xffff0000u); }

// ---------------- conv: 576 blocks, 16x4 px tile; wave w: 3x3 co-pair {2w,2w+1} (fp32 xe)
//                  + 1x1 co 8w..8w+7 written DIRECTLY as bf16 Vu rows ----------------
__global__ __launch_bounds__(256) void k_conv(const float* __restrict__ x,
    const float* __restrict__ wm, const float* __restrict__ bm,
    const float* __restrict__ wa, const float* __restrict__ ba,
    float* __restrict__ xe, u16* __restrict__ Vu)
{
  __shared__ float xs[32*108];   // 32 ci x 6x18 halo
  const int t = threadIdx.x;
  const int id = blockIdx.x;
  const int bx = id % 12, by = id / 12;

  for (int idx=t; idx<3456; idx+=256){
    int ci = idx/108, rem = idx-ci*108;
    int iy = rem/18,  ix = rem-iy*18;
    int yy = by*4+iy-1, xx = bx*16+ix-1;
    float v = 0.f;
    if (yy>=0 && yy<HW_ && xx>=0 && xx<HW_) v = x[ci*LTOT + yy*HW_ + xx];
    xs[idx] = v;
  }
  __syncthreads();
  const int lane = t & 63;
  const int w  = __builtin_amdgcn_readfirstlane(t>>6);
  const int co0 = 2*w, cb = 8*w;
  const int ix = lane & 15, iy = lane >> 4;
  float a0 = bm[co0], a1 = bm[co0+1];
  float acc[8];
  #pragma unroll
  for (int co=0;co<8;co++) acc[co] = ba[cb+co];
  const float* xb  = xs + iy*18 + ix;
  const float* w0p = wm + co0*288;
  const float* w1p = w0p + 288;
  for (int ci=0; ci<32; ci++){
    const float* xp = xb + ci*108;
    float x00=xp[0],  x01=xp[1],  x02=xp[2];
    float x10=xp[18], x11=xp[19], x12=xp[20];
    float x20=xp[36], x21=xp[37], x22=xp[38];
    const float* w0 = w0p + ci*9;
    const float* w1 = w1p + ci*9;
    a0 += x00*w0[0]+x01*w0[1]+x02*w0[2]
        + x10*w0[3]+x11*w0[4]+x12*w0[5]
        + x20*w0[6]+x21*w0[7]+x22*w0[8];
    a1 += x00*w1[0]+x01*w1[1]+x02*w1[2]
        + x10*w1[3]+x11*w1[4]+x12*w1[5]
        + x20*w1[6]+x21*w1[7]+x22*w1[8];
    const float* wap = wa + cb*32 + ci;
    #pragma unroll
    for (int co=0;co<8;co++) acc[co] += x11 * wap[co*32];
  }
  const int l = (by*4+iy)*HW_ + bx*16+ix;
  *(float2*)(xe + l*8 + co0) = float2{a0,a1};
  uint4 vv;
  vv.x = pkbf(acc[0],acc[1]); vv.y = pkbf(acc[2],acc[3]);
  vv.z = pkbf(acc[4],acc[5]); vv.w = pkbf(acc[6],acc[7]);
  *(uint4*)(Vu + (size_t)l*32 + cb) = vv;
}

// ---------------- hash + stable local rank (merged), ballot-based ----------------
__global__ __launch_bounds__(256) void k_hashrank(const float* __restrict__ xe,
    const float* __restrict__ rot, int* __restrict__ code,
    int* __restrict__ lrank, int* __restrict__ hist)
{
  const int h = blockIdx.y, seg = blockIdx.x, t = threadIdx.x;
  const int l = seg*256 + t;
  const float4* qp = (const float4*)(xe + l*8);
  float4 qa = qp[0], qb = qp[1];
  float best = -INFINITY; int bi = 0;
  float worst = INFINITY; int wi = 0;
  for (int i=0; i<64; i++){
    const float* rp = rot + h*64 + i;   // rot[f*256 + h*64 + i]
    float v = qa.x*rp[0]    + qa.y*rp[256]  + qa.z*rp[512]  + qa.w*rp[768]
            + qb.x*rp[1024] + qb.y*rp[1280] + qb.z*rp[1536] + qb.w*rp[1792];
    if (v > best)  { best  = v; bi = i; }
    if (v < worst) { worst = v; wi = i; }
  }
  int c = (-worst > best) ? (64+wi) : bi;
  code[h*LTOT + l] = c;

  const int lane = t & 63, w = t >> 6;
  u64 mask = ~0ull;
  #pragma unroll
  for (int bit=0; bit<7; bit++){
    u64 bset = __ballot((c>>bit)&1);
    mask &= ((c>>bit)&1) ? bset : ~bset;
  }
  int rin = __popcll(mask & ((lane==0)?0ull:(~0ull >> (64-lane))));
  int cnt = __popcll(mask);

  __shared__ int wh[4][NBUCK];
  ((int*)wh)[t] = 0; ((int*)wh)[t+256] = 0;
  __syncthreads();
  if (rin == 0) wh[w][c] = cnt;
  __syncthreads();
  int r = rin;
  for (int ww=0; ww<w; ww++) r += wh[ww][c];
  lrank[h*LTOT + l] = r;
  if (t < NBUCK) hist[(h*NSEG+seg)*NBUCK + t] = wh[0][t]+wh[1][t]+wh[2][t]+wh[3][t];
}

// ---------------- bucket/segment prefix scan ----------------
__global__ __launch_bounds__(512) void k_scan(const int* __restrict__ hist,
    int* __restrict__ segoff)
{
  const int h = blockIdx.x;
  const int b = threadIdx.x & 127, g = threadIdx.x >> 7;
  int vals[36];
  int sum = 0;
  #pragma unroll
  for (int i=0;i<36;i++){
    vals[i] = hist[(h*NSEG + g*36 + i)*NBUCK + b];
    sum += vals[i];
  }
  __shared__ int ps[4][NBUCK];
  __shared__ int tot[NBUCK];
  __shared__ int scv[NBUCK];
  ps[g][b] = sum;
  __syncthreads();
  if (g == 0){
    int run = 0;
    #pragma unroll
    for (int gg=0; gg<4; gg++){ int tv = ps[gg][b]; ps[gg][b] = run; run += tv; }
    tot[b] = run;
    int v = run;
    #pragma unroll
    for (int off=1; off<64; off<<=1){
      int u = __shfl_up(v, off);
      if ((b & 63) >= off) v += u;
    }
    scv[b] = v;
  }
  __syncthreads();
  int base = scv[b] - tot[b] + ((b >= 64) ? scv[63] : 0);
  int run2 = base + ps[g][b];
  #pragma unroll
  for (int i=0;i<36;i++){
    segoff[(h*NSEG + g*36 + i)*NBUCK + b] = run2;
    run2 += vals[i];
  }
}

// ---------------- scatter: sorted bf16 K/Q (16B rows), V (64B row copy), spos ----------------
__global__ __launch_bounds__(256) void k_scatter(const int* __restrict__ code,
    const int* __restrict__ lrank, const int* __restrict__ segoff,
    const float* __restrict__ xe, const u16* __restrict__ Vu,
    int* __restrict__ spos, u16* __restrict__ Ks, u16* __restrict__ Qs,
    u16* __restrict__ Vs)
{
  const int h = blockIdx.y, seg = blockIdx.x, t = threadIdx.x;
  const int l = seg*256 + t;
  int c = code[h*LTOT + l];
  int r = segoff[(h*NSEG+seg)*NBUCK + c] + lrank[h*LTOT + l];
  spos[h*LTOT + r] = l;

  const float4* xr = (const float4*)(xe + l*8);
  float4 a = xr[0], b = xr[1];
  float n2 = a.x*a.x+a.y*a.y+a.z*a.z+a.w*a.w
           + b.x*b.x+b.y*b.y+b.z*b.z+b.w*b.w;
  float sc = 1.0f / fmaxf(sqrtf(n2), 5e-5f);
  uint4 kk, qq;
  kk.x = pkbf(a.x*sc,a.y*sc); kk.y = pkbf(a.z*sc,a.w*sc);
  kk.z = pkbf(b.x*sc,b.y*sc); kk.w = pkbf(b.z*sc,b.w*sc);
  qq.x = pkbf(a.x,a.y); qq.y = pkbf(a.z,a.w);
  qq.z = pkbf(b.x,b.y); qq.w = pkbf(b.z,b.w);
  *(uint4*)(Ks + (size_t)(h*LTOT + r)*8) = kk;
  *(uint4*)(Qs + (size_t)(h*LTOT + r)*8) = qq;

  const uint4* vr = (const uint4*)(Vu + (size_t)l*32);
  uint4* vp = (uint4*)(Vs + (size_t)(h*LTOT + r)*32);
  vp[0] = vr[0]; vp[1] = vr[1]; vp[2] = vr[2]; vp[3] = vr[3];
}

// ---------------- chunked attention: all-K upfront, double-buffered VT, reg-prefetched V;
//                  2 barriers in the region loop; outputs scattered to unsorted order ----------------
__global__ __launch_bounds__(320) void k_attn(const u16* __restrict__ Ks,
    const u16* __restrict__ Qs, const u16* __restrict__ Vs,
    const int* __restrict__ spos, u16* __restrict__ ret_u, float* __restrict__ bs_u)
{
  __shared__ __align__(16) u16 Klds[432*8];      // all 3 regions' keys (region-major)
  __shared__ __align__(16) u16 Qlds[CHU*8];
  __shared__ __align__(16) u16 VT[2][32*VTS];    // double-buffered V^T [e][key]
  __shared__ float qn[CHU];
  __shared__ int spos_l[CHU];

  const int t = threadIdx.x;
  const int k = blockIdx.x, h = blockIdx.y;
  const int vp_i = t - 176, vp_p = vp_i >> 1, vp_hf = vp_i & 1;

  uint4 vpa0, vpa1, vpb0, vpb1;

  // phase 0: stage Q/qn/spos + ALL K (t<144: 3 rows each); V region0 -> regs (t>=176)
  if (t < CHU){
    uint4 qv = *(const uint4*)(Qs + (size_t)(h*LTOT + k*CHU + t)*8);
    *(uint4*)(Qlds + t*8) = qv;
    float f0=bflo(qv.x), f1=bfhi(qv.x), f2=bflo(qv.y), f3=bfhi(qv.y);
    float f4=bflo(qv.z), f5=bfhi(qv.z), f6=bflo(qv.w), f7=bfhi(qv.w);
    qn[t] = sqrtf(f0*f0+f1*f1+f2*f2+f3*f3+f4*f4+f5*f5+f6*f6+f7*f7)*1.01f + 1e-6f;
    spos_l[t] = spos[h*LTOT + k*CHU + t];
    #pragma unroll
    for (int rr=0; rr<3; rr++){
      const int gkb = ((k + NCHUNK-1 + rr) & (NCHUNK-1)) * CHU;
      *(uint4*)(Klds + (rr*CHU + t)*8) =
          *(const uint4*)(Ks + (size_t)(h*LTOT + gkb + t)*8);
    }
  } else if (t >= 176){
    const int gkb = ((k + NCHUNK-1) & (NCHUNK-1)) * CHU;
    const uint4* ra = (const uint4*)(Vs + (size_t)(h*LTOT + gkb + 2*vp_p)*32);
    const uint4* rb = (const uint4*)(Vs + (size_t)(h*LTOT + gkb + 2*vp_p+1)*32);
    vpa0 = ra[vp_hf*2]; vpa1 = ra[vp_hf*2+1];
    vpb0 = rb[vp_hf*2]; vpb1 = rb[vp_hf*2+1];
  }
  if (t >= 176){
    u32 aw[8] = {vpa0.x,vpa0.y,vpa0.z,vpa0.w,vpa1.x,vpa1.y,vpa1.z,vpa1.w};
    u32 bw[8] = {vpb0.x,vpb0.y,vpb0.z,vpb0.w,vpb1.x,vpb1.y,vpb1.z,vpb1.w};
    int ebase = vp_hf*16;
    #pragma unroll
    for (int m=0;m<8;m++){
      u32 al = aw[m]&0xffffu, ah = aw[m]>>16;
      u32 bl = bw[m]&0xffffu, bh = bw[m]>>16;
      VT[0][(ebase+2*m  )*VTS + 2*vp_p] |= 0;   // keep layout; direct stores below
      *(u32*)&VT[0][(ebase+2*m  )*VTS + 2*vp_p] = al | (bl<<16);
      *(u32*)&VT[0][(ebase+2*m+1)*VTS + 2*vp_p] = ah | (bh<<16);
    }
  }
  __syncthreads();

  const int lane = t & 63;
  const int wv = t >> 6;                 // 0..4
  const int q = lane & 15;
  const int quad = lane >> 4;
  const bool two = (wv < 4);
  const int tl0 = 2*wv;
  const int tl1 = two ? (2*wv+1) : 8;

  const short4v zs = {0,0,0,0};
  short4v bq0 = zs, bq1 = zs;
  if (quad < 2){
    bq0 = *(const short4v*)(Qlds + (tl0*16+q)*8 + quad*4);
    if (two) bq1 = *(const short4v*)(Qlds + (tl1*16+q)*8 + quad*4);
  }
  const float m0 = qn[tl0*16+q];
  const float m1 = two ? qn[tl1*16+q] : 0.f;

  f32x4 o00={0,0,0,0}, o01={0,0,0,0}, o10={0,0,0,0}, o11={0,0,0,0};
  float s0 = 0.f, s1 = 0.f;

  for (int r=0; r<3; r++){
    // prefetch next region's V into regs (overlaps this region's compute)
    if (r < 2 && t >= 176){
      const int gkb = ((k + NCHUNK + r) & (NCHUNK-1)) * CHU;
      const uint4* ra = (const uint4*)(Vs + (size_t)(h*LTOT + gkb + 2*vp_p)*32);
      const uint4* rb = (const uint4*)(Vs + (size_t)(h*LTOT + gkb + 2*vp_p+1)*32);
      vpa0 = ra[vp_hf*2]; vpa1 = ra[vp_hf*2+1];
      vpb0 = rb[vp_hf*2]; vpb1 = rb[vp_hf*2+1];
    }
    const u16* vtb = VT[r & 1];

    #pragma unroll 3
    for (int kt=0; kt<9; kt++){
      short4v av = zs;
      if (quad < 2) av = *(const short4v*)(Klds + ((r*9+kt)*16+q)*8 + quad*4);
      f32x4 zc = {0.f,0.f,0.f,0.f};
      f32x4 stA = __builtin_amdgcn_mfma_f32_16x16x16bf16_1k(av, bq0, zc, 0,0,0);

      float pA0 = __expf(stA[0]-m0), pA1 = __expf(stA[1]-m0);
      float pA2 = __expf(stA[2]-m0), pA3 = __expf(stA[3]-m0);
      s0 += (pA0+pA1)+(pA2+pA3);
      union { u32 u[2]; short4v s4; } pkA;
      pkA.u[0] = pkbf(pA0,pA1); pkA.u[1] = pkbf(pA2,pA3);

      short4v va0 = *(const short4v*)(&vtb[ q    *VTS + kt*16 + quad*4]);
      short4v va1 = *(const short4v*)(&vtb[(q+16)*VTS + kt*16 + quad*4]);
      o00 = __builtin_amdgcn_mfma_f32_16x16x16bf16_1k(va0, pkA.s4, o00, 0,0,0);
      o01 = __builtin_amdgcn_mfma_f32_16x16x16bf16_1k(va1, pkA.s4, o01, 0,0,0);

      if (two){
        f32x4 stB = __builtin_amdgcn_mfma_f32_16x16x16bf16_1k(av, bq1, zc, 0,0,0);
        float pB0 = __expf(stB[0]-m1), pB1 = __expf(stB[1]-m1);
        float pB2 = __expf(stB[2]-m1), pB3 = __expf(stB[3]-m1);
        s1 += (pB0+pB1)+(pB2+pB3);
        union { u32 u[2]; short4v s4; } pkB;
        pkB.u[0] = pkbf(pB0,pB1); pkB.u[1] = pkbf(pB2,pB3);
        o10 = __builtin_amdgcn_mfma_f32_16x16x16bf16_1k(va0, pkB.s4, o10, 0,0,0);
        o11 = __builtin_amdgcn_mfma_f32_16x16x16bf16_1k(va1, pkB.s4, o11, 0,0,0);
      }
    }

    if (r < 2){
      // write prefetched regs into the OTHER buffer (its readers finished
      // before this region's start barrier), then one barrier
      if (t >= 176){
        u32 aw[8] = {vpa0.x,vpa0.y,vpa0.z,vpa0.w,vpa1.x,vpa1.y,vpa1.z,vpa1.w};
        u32 bw[8] = {vpb0.x,vpb0.y,vpb0.z,vpb0.w,vpb1.x,vpb1.y,vpb1.z,vpb1.w};
        int ebase = vp_hf*16;
        u16* vtn = (u16*)VT[(r+1) & 1];
        #pragma unroll
        for (int m=0;m<8;m++){
          u32 al = aw[m]&0xffffu, ah = aw[m]>>16;
          u32 bl = bw[m]&0xffffu, bh = bw[m]>>16;
          *(u32*)&vtn[(ebase+2*m  )*VTS + 2*vp_p] = al | (bl<<16);
          *(u32*)&vtn[(ebase+2*m+1)*VTS + 2*vp_p] = ah | (bh<<16);
        }
      }
      __syncthreads();
    }
  }

  float st0 = s0;
  st0 += __shfl_xor(st0, 16); st0 += __shfl_xor(st0, 32);
  float inv0 = 1.0f/st0;

  const int pos0 = spos_l[tl0*16 + q];
  u16* rp0 = ret_u + (size_t)(h*LTOT + pos0)*32;
  uint2 wA, wB;
  wA.x = pkbf(o00[0]*inv0, o00[1]*inv0); wA.y = pkbf(o00[2]*inv0, o00[3]*inv0);
  wB.x = pkbf(o01[0]*inv0, o01[1]*inv0); wB.y = pkbf(o01[2]*inv0, o01[3]*inv0);
  *(uint2*)&rp0[quad*4]    = wA;
  *(uint2*)&rp0[16+quad*4] = wB;
  if (quad == 0) bs_u[h*LTOT + pos0] = m0 + __logf(st0);

  if (two){
    float st1 = s1;
    st1 += __shfl_xor(st1, 16); st1 += __shfl_xor(st1, 32);
    float inv1 = 1.0f/st1;
    const int pos1 = spos_l[tl1*16 + q];
    u16* rp1 = ret_u + (size_t)(h*LTOT + pos1)*32;
    wA.x = pkbf(o10[0]*inv1, o10[1]*inv1); wA.y = pkbf(o10[2]*inv1, o10[3]*inv1);
    wB.x = pkbf(o11[0]*inv1, o11[1]*inv1); wB.y = pkbf(o11[2]*inv1, o11[3]*inv1);
    *(uint2*)&rp1[quad*4]    = wA;
    *(uint2*)&rp1[16+quad*4] = wB;
    if (quad == 0) bs_u[h*LTOT + pos1] = m1 + __logf(st1);
  }
}

// ---------------- cross-hash softmax + residual — fully coalesced ----------------
__global__ __launch_bounds__(256) void k_final(const float* __restrict__ x,
    const u16* __restrict__ ret_u, const float* __restrict__ bs_u,
    float* __restrict__ out)
{
  const int l  = blockIdx.x*64 + (threadIdx.x & 63);
  const int eg = threadIdx.x >> 6;
  float bs[NH];
  #pragma unroll
  for (int h=0;h<NH;h++) bs[h] = bs_u[h*LTOT + l];
  float m = fmaxf(fmaxf(bs[0],bs[1]), fmaxf(bs[2],bs[3]));
  float p[NH]; float s = 0.f;
  #pragma unroll
  for (int h=0;h<NH;h++){ p[h] = __expf(bs[h]-m); s += p[h]; }
  float inv = 1.0f/s;
  float o[8];
  #pragma unroll
  for (int e=0;e<8;e++) o[e]=0.f;
  #pragma unroll
  for (int h=0;h<NH;h++){
    float w = p[h]*inv;
    uint4 v = *(const uint4*)(ret_u + (size_t)(h*LTOT + l)*32 + eg*8);
    o[0] += w*bflo(v.x); o[1] += w*bfhi(v.x);
    o[2] += w*bflo(v.y); o[3] += w*bfhi(v.y);
    o[4] += w*bflo(v.z); o[5] += w*bfhi(v.z);
    o[6] += w*bflo(v.w); o[7] += w*bfhi(v.w);
  }
  #pragma unroll
  for (int e=0;e<8;e++){
    int ge = eg*8 + e;
    out[ge*LTOT + l] = o[e] + x[ge*LTOT + l];
  }
}

extern "C" void kernel_launch(void* const* d_in, const int* in_sizes, int n_in,
                              void* d_out, int out_size, void* d_ws, size_t ws_size,
                              hipStream_t stream)
{
  const float* x   = (const float*)d_in[0];
  const float* wm  = (const float*)d_in[1];
  const float* bm  = (const float*)d_in[2];
  const float* wa  = (const float*)d_in[3];
  const float* ba  = (const float*)d_in[4];
  const float* rot = (const float*)d_in[5];
  float* out = (float*)d_out;

  char* ws = (char*)d_ws;
  size_t off = 0;
  auto alloc = [&](size_t bytes)->void*{
    void* p = ws + off;
    off = (off + bytes + 255) & ~(size_t)255;
    return p;
  };
  float* xe     = (float*)alloc((size_t)LTOT*8*4);
  u16*   Vu     = (u16*)  alloc((size_t)LTOT*32*2);
  int*   code   = (int*)  alloc((size_t)NH*LTOT*4);
  int*   lrank  = (int*)  alloc((size_t)NH*LTOT*4);
  int*   hist   = (int*)  alloc((size_t)NH*NSEG*NBUCK*4);
  int*   segoff = (int*)  alloc((size_t)NH*NSEG*NBUCK*4);
  int*   spos   = (int*)  alloc((size_t)NH*LTOT*4);
  u16*   Ks     = (u16*)  alloc((size_t)NH*LTOT*8*2);
  u16*   Qs     = (u16*)  alloc((size_t)NH*LTOT*8*2);
  u16*   Vs     = (u16*)  alloc((size_t)NH*LTOT*32*2);
  u16*   ret_u  = (u16*)  alloc((size_t)NH*LTOT*32*2);
  float* bs_u   = (float*)alloc((size_t)NH*LTOT*4);

  hipLaunchKernelGGL(k_conv,     dim3(576),        dim3(256), 0, stream, x, wm, bm, wa, ba, xe, Vu);
  hipLaunchKernelGGL(k_hashrank, dim3(NSEG,NH),    dim3(256), 0, stream, xe, rot, code, lrank, hist);
  hipLaunchKernelGGL(k_scan,     dim3(NH),         dim3(512), 0, stream, hist, segoff);
  hipLaunchKernelGGL(k_scatter,  dim3(NSEG,NH),    dim3(256), 0, stream, code, lrank, segoff, xe, Vu, spos, Ks, Qs, Vs);
  hipLaunchKernelGGL(k_attn,     dim3(NCHUNK,NH),  dim3(320), 0, stream, Ks, Qs, Vs, spos, ret_u, bs_u);
  hipLaunchKernelGGL(k_final,    dim3(576),        dim3(256), 0, stream, x, ret_u, bs_u, out);
}